// Round 1
// baseline (212.255 us; speedup 1.0000x reference)
//
#include <hip/hip_runtime.h>

// Truncated path signature, level M=4, d=10, L=256.
// One thread owns output pair (i,j): S1[i], S2[i,j], S3[i,j,*] (10), S4[i,j,*,*] (100).
// Per step (increment v), with OLD carry values:
//   S4[ijkl] += ((v_i v_j/24 + S1_i v_j/6 + S2_ij/2) * v_k + S3[ijk]) * v_l
//   S3[ijk]  += (v_i v_j/6  + S1_i v_j/2 + S2_ij) * v_k
//   S2[ij]   += (v_i/2 + S1_i) * v_j
//   S1[i]    += v_i
// 100 active threads per batch; block = 256 threads = 2 batches (lanes 100..127 idle).

#define D      10
#define LPATH  256
#define SIGTOT 11110   // 10 + 100 + 1000 + 10000

__global__ __launch_bounds__(256, 2)
void sig_kernel(const float* __restrict__ x, float* __restrict__ out) {
    __shared__ float lx[2 * LPATH * D];   // 2 batches * 2560 floats = 20 KB
    const int tid = threadIdx.x;
    const int blk = blockIdx.x;

    // cooperative stage: 5120 floats = 1280 float4, 5 per thread, coalesced
    {
        const float4* src = (const float4*)(x + (size_t)blk * (2 * LPATH * D));
        float4* dst = (float4*)lx;
        #pragma unroll
        for (int r = 0; r < 5; ++r)
            dst[r * 256 + tid] = src[r * 256 + tid];
    }
    __syncthreads();

    const int bl = tid >> 7;        // which of the 2 batches in this block
    const int p  = tid & 127;       // pair index within batch
    if (p >= 100) return;           // no further __syncthreads below
    const int i = p / 10;
    const int j = p - i * 10;
    const float* bx = lx + bl * (LPATH * D);

    float s1 = 0.f, s2 = 0.f;
    float s3[D];
    float s4[100];
    #pragma unroll
    for (int k = 0; k < D; ++k) s3[k] = 0.f;
    #pragma unroll
    for (int k = 0; k < 100; ++k) s4[k] = 0.f;

    // previous path point: full row (static regs) + the two runtime-indexed lanes
    float xp[D];
    #pragma unroll
    for (int q = 0; q < D; ++q) xp[q] = bx[q];
    float xpi = bx[i];
    float xpj = bx[j];

    for (int t = 1; t < LPATH; ++t) {
        const float* row = bx + t * D;
        float v[D];
        #pragma unroll
        for (int q = 0; q < D; ++q) {
            float xn = row[q]; v[q] = xn - xp[q]; xp[q] = xn;
        }
        float xni = row[i]; const float vi = xni - xpi; xpi = xni;  // LDS broadcast reads
        float xnj = row[j]; const float vj = xnj - xpj; xpj = xnj;

        const float b = vj * (vi * (1.f/24.f) + s1 * (1.f/6.f)) + s2 * 0.5f;
        const float a = vj * (vi * (1.f/6.f)  + s1 * 0.5f)      + s2;

        float c[D];
        #pragma unroll
        for (int k = 0; k < D; ++k) c[k] = b * v[k] + s3[k];   // captures OLD s3
        #pragma unroll
        for (int k = 0; k < D; ++k) s3[k] += a * v[k];
        #pragma unroll
        for (int k = 0; k < D; ++k) {
            #pragma unroll
            for (int l = 0; l < D; ++l)
                s4[k * 10 + l] += c[k] * v[l];                 // 100 independent FMAs
        }
        s2 += vj * (vi * 0.5f + s1);                           // OLD s1
        s1 += vi;
    }

    // epilogue: layout [S1(10) | S2(100) | S3(1000) | S4(10000)] per batch
    const size_t ob = ((size_t)blk * 2 + bl) * (size_t)SIGTOT;
    if (j == 0) out[ob + i] = s1;
    out[ob + 10 + p] = s2;
    #pragma unroll
    for (int k = 0; k < D; ++k) out[ob + 110 + p * 10 + k] = s3[k];
    #pragma unroll
    for (int k = 0; k < 100; ++k) out[ob + 1110 + p * 100 + k] = s4[k];
}

extern "C" void kernel_launch(void* const* d_in, const int* in_sizes, int n_in,
                              void* d_out, int out_size, void* d_ws, size_t ws_size,
                              hipStream_t stream) {
    const float* x = (const float*)d_in[0];
    float* out = (float*)d_out;
    const int B = in_sizes[0] / (LPATH * D);   // 2048
    const int nblocks = B / 2;                 // 1024 blocks, 2 batches each
    sig_kernel<<<nblocks, 256, 0, stream>>>(x, out);
}